// Round 7
// baseline (61.603 us; speedup 1.0000x reference)
//
#include <hip/hip_runtime.h>

#define CURIOSITY_COEF 0.1f
#define EPS_F 1e-8f

typedef float f32x4 __attribute__((ext_vector_type(4)));
typedef int   i32x4 __attribute__((ext_vector_type(4)));

// Quad-lane (aligned 4-lane cluster) exchanges via DPP quad_perm: pure VALU.
// xor1: [1,0,3,2] -> ctrl 0xB1 ; xor2: [2,3,0,1] -> ctrl 0x4E
__device__ __forceinline__ float fqxor1(float x) {
    return __int_as_float(__builtin_amdgcn_mov_dpp(__float_as_int(x), 0xB1, 0xF, 0xF, true));
}
__device__ __forceinline__ float fqxor2(float x) {
    return __int_as_float(__builtin_amdgcn_mov_dpp(__float_as_int(x), 0x4E, 0xF, 0xF, true));
}
__device__ __forceinline__ int iqxor1(int x) {
    return __builtin_amdgcn_mov_dpp(x, 0xB1, 0xF, 0xF, true);
}
__device__ __forceinline__ int iqxor2(int x) {
    return __builtin_amdgcn_mov_dpp(x, 0x4E, 0xF, 0xF, true);
}

// One quarter-group (4 elements of a 16-group, the group spread across the
// aligned 4-lane cluster): masked min/max/count via DPP butterfly, then
// out = fma(r, a, b) with sign/scale/min/singleton folded into (a, b).
__device__ __forceinline__ f32x4 process_qgroup(f32x4 rr, i32x4 cc) {
    float v[4]  = {rr.x, rr.y, rr.z, rr.w};
    int   cm[4] = {cc.x, cc.y, cc.z, cc.w};

    float minC = INFINITY, nmxC = INFINITY;   // nmxC = -maxC
    float minI = INFINITY, nmxI = INFINITY;   // nmxI = -maxI
    int   cnt  = 0;
    #pragma unroll
    for (int e = 0; e < 4; ++e) {
        bool  c = (cm[e] != 0);
        float x = v[e];
        minC = fminf(minC, c ?  x : INFINITY);
        nmxC = fminf(nmxC, c ? -x : INFINITY);
        minI = fminf(minI, c ? INFINITY :  x);
        nmxI = fminf(nmxI, c ? INFINITY : -x);
        cnt += c ? 1 : 0;
    }

    minC = fminf(minC, fqxor1(minC));
    nmxC = fminf(nmxC, fqxor1(nmxC));
    minI = fminf(minI, fqxor1(minI));
    nmxI = fminf(nmxI, fqxor1(nmxI));
    cnt += iqxor1(cnt);
    minC = fminf(minC, fqxor2(minC));
    nmxC = fminf(nmxC, fqxor2(nmxC));
    minI = fminf(minI, fqxor2(minI));
    nmxI = fminf(nmxI, fqxor2(nmxI));
    cnt += iqxor2(cnt);

    int cntC = cnt;
    int cntI = 16 - cnt;

    float dC   = -nmxC - minC + EPS_F;         // maxC - minC + eps
    float dI   = -nmxI - minI + EPS_F;
    float invC = __builtin_amdgcn_rcpf(dC);    // rel err ~2^-22, << tolerance
    float invI = __builtin_amdgcn_rcpf(dI);
    float aC =  CURIOSITY_COEF * invC;
    float bC = -aC * minC;
    float aI = -CURIOSITY_COEF * invI;
    float bI = -aI * minI;
    if (cntC == 1) { aC = 0.0f; bC =  0.05f; } // n = 0.5 exactly
    if (cntI == 1) { aI = 0.0f; bI = -0.05f; }
    // Empty stratum -> inf/nan in (a,b), but only on the never-selected side.

    f32x4 ov;
    #pragma unroll
    for (int e = 0; e < 4; ++e) {
        bool  c = (cm[e] != 0);
        ov[e] = fmaf(v[e], c ? aC : aI, c ? bC : bI);
    }
    return ov;
}

// ILP=2, cluster-aligned: each aligned 4-lane cluster c owns TWO consecutive
// whole groups. Thread t (lane-in-cluster l = t&3) processes q0 = 8(t>>2)+l
// (group 2c) and q1 = q0+4 (group 2c+1) -- the DPP butterfly stays within one
// group for both iterations (R6's 2t/2t+1 mapping mixed two groups: bug).
// All 4 loads issue before compute -> 4 vmem requests in flight per thread.
__global__ __launch_bounds__(256) void srnd_kernel(
    const f32x4* __restrict__ r4,
    const i32x4* __restrict__ c4,
    f32x4*       __restrict__ o4,
    int T)  // T = Q/2 = number of threads
{
    int t = blockIdx.x * blockDim.x + threadIdx.x;
    if (t >= T) return;
    int q0 = ((t >> 2) << 3) + (t & 3);
    int q1 = q0 + 4;

    f32x4 rr0 = r4[q0];
    i32x4 cc0 = c4[q0];
    f32x4 rr1 = r4[q1];
    i32x4 cc1 = c4[q1];

    f32x4 ov0 = process_qgroup(rr0, cc0);
    f32x4 ov1 = process_qgroup(rr1, cc1);

    __builtin_nontemporal_store(ov0, &o4[q0]);
    __builtin_nontemporal_store(ov1, &o4[q1]);
}

extern "C" void kernel_launch(void* const* d_in, const int* in_sizes, int n_in,
                              void* d_out, int out_size, void* d_ws, size_t ws_size,
                              hipStream_t stream) {
    const float* rewards = (const float*)d_in[0];
    const int*   corr    = (const int*)d_in[1];
    float*       out     = (float*)d_out;

    int N = in_sizes[0];
    int Q = N / 4;   // quarter-groups (group_size = 16 -> 4 lanes/group)
    int T = Q / 2;   // two groups per 4-lane cluster

    const int threads = 256;
    const int blocks  = (T + threads - 1) / threads;
    srnd_kernel<<<blocks, threads, 0, stream>>>(
        reinterpret_cast<const f32x4*>(rewards),
        reinterpret_cast<const i32x4*>(corr),
        reinterpret_cast<f32x4*>(out), T);
}

// Round 8
// 60.074 us; speedup vs baseline: 1.0255x; 1.0255x over previous
//
#include <hip/hip_runtime.h>

#define CURIOSITY_COEF 0.1f
#define EPS_F 1e-8f

typedef float f32x4 __attribute__((ext_vector_type(4)));
typedef int   i32x4 __attribute__((ext_vector_type(4)));

// Quad-lane (aligned 4-lane cluster) exchanges via DPP quad_perm: pure VALU.
// xor1: [1,0,3,2] -> ctrl 0xB1 ; xor2: [2,3,0,1] -> ctrl 0x4E
__device__ __forceinline__ float fqxor1(float x) {
    return __int_as_float(__builtin_amdgcn_mov_dpp(__float_as_int(x), 0xB1, 0xF, 0xF, true));
}
__device__ __forceinline__ float fqxor2(float x) {
    return __int_as_float(__builtin_amdgcn_mov_dpp(__float_as_int(x), 0x4E, 0xF, 0xF, true));
}
__device__ __forceinline__ int iqxor1(int x) {
    return __builtin_amdgcn_mov_dpp(x, 0xB1, 0xF, 0xF, true);
}
__device__ __forceinline__ int iqxor2(int x) {
    return __builtin_amdgcn_mov_dpp(x, 0x4E, 0xF, 0xF, true);
}

// Streaming store with ALL cache-policy bits set (sc0 sc1 nt): the only
// ISA-visible knob that could make the output write-around instead of
// allocating in the memory-side Infinity Cache. If it works, both input
// arrays (256 MiB) stay L3-resident and HBM fetch drops to ~0.
__device__ __forceinline__ void stream_store(f32x4* p, f32x4 v) {
    asm volatile("global_store_dwordx4 %0, %1, off sc0 sc1 nt"
                 :: "v"(p), "v"(v) : "memory");
}

// R5 structure (known-best 59.5us): 4 lanes per group of 16, one contiguous
// float4/int4 (16B) per lane -> every wave-level access covers a contiguous
// 4KB span; ONE quarter-group per thread keeps VGPR at 16-20 so occupancy
// stays at the TLP cap (R4/R7 showed ILP batching is neutral-to-negative).
__global__ __launch_bounds__(256) void srnd_kernel(
    const f32x4* __restrict__ r4,
    const i32x4* __restrict__ c4,
    f32x4*       __restrict__ o4,
    int Q)  // Q = number of quarter-groups = B*4
{
    int q = blockIdx.x * blockDim.x + threadIdx.x;
    if (q >= Q) return;

    f32x4 rr = r4[q];
    i32x4 cc = c4[q];
    float v[4]  = {rr.x, rr.y, rr.z, rr.w};
    int   cm[4] = {cc.x, cc.y, cc.z, cc.w};

    // Masked min accumulators; max tracked as min of negated values so every
    // accumulator uses the same +INF fill (-x is a free VOP3 input modifier).
    float minC = INFINITY, nmxC = INFINITY;   // nmxC = -maxC
    float minI = INFINITY, nmxI = INFINITY;   // nmxI = -maxI
    int   cnt  = 0;
    #pragma unroll
    for (int e = 0; e < 4; ++e) {
        bool  c = (cm[e] != 0);
        float x = v[e];
        minC = fminf(minC, c ?  x : INFINITY);
        nmxC = fminf(nmxC, c ? -x : INFINITY);
        minI = fminf(minI, c ? INFINITY :  x);
        nmxI = fminf(nmxI, c ? INFINITY : -x);
        cnt += c ? 1 : 0;
    }

    // Quad butterfly via DPP (group = aligned 4-lane cluster).
    minC = fminf(minC, fqxor1(minC));
    nmxC = fminf(nmxC, fqxor1(nmxC));
    minI = fminf(minI, fqxor1(minI));
    nmxI = fminf(nmxI, fqxor1(nmxI));
    cnt += iqxor1(cnt);
    minC = fminf(minC, fqxor2(minC));
    nmxC = fminf(nmxC, fqxor2(nmxC));
    minI = fminf(minI, fqxor2(minI));
    nmxI = fminf(nmxI, fqxor2(nmxI));
    cnt += iqxor2(cnt);

    int cntC = cnt;
    int cntI = 16 - cnt;

    // out = sign * 0.1 * (r - min) * inv == fma(r, a, b); v_rcp_f32 rel err
    // ~2^-22 -> ~1e-8 abs on the 0.1-scaled output, far below tolerance.
    float dC   = -nmxC - minC + EPS_F;         // maxC - minC + eps
    float dI   = -nmxI - minI + EPS_F;
    float invC = __builtin_amdgcn_rcpf(dC);
    float invI = __builtin_amdgcn_rcpf(dI);
    float aC =  CURIOSITY_COEF * invC;
    float bC = -aC * minC;
    float aI = -CURIOSITY_COEF * invI;
    float bI = -aI * minI;
    if (cntC == 1) { aC = 0.0f; bC =  0.05f; } // n = 0.5 exactly
    if (cntI == 1) { aI = 0.0f; bI = -0.05f; }
    // Empty stratum -> inf/nan in (a,b), but only on the never-selected side.

    f32x4 ov;
    #pragma unroll
    for (int e = 0; e < 4; ++e) {
        bool  c = (cm[e] != 0);
        ov[e] = fmaf(v[e], c ? aC : aI, c ? bC : bI);
    }

    stream_store(&o4[q], ov);
}

extern "C" void kernel_launch(void* const* d_in, const int* in_sizes, int n_in,
                              void* d_out, int out_size, void* d_ws, size_t ws_size,
                              hipStream_t stream) {
    const float* rewards = (const float*)d_in[0];
    const int*   corr    = (const int*)d_in[1];
    float*       out     = (float*)d_out;

    int N = in_sizes[0];
    int Q = N / 4;  // quarter-groups (group_size = 16 -> 4 lanes/group)

    const int threads = 256;
    const int blocks  = (Q + threads - 1) / threads;
    srnd_kernel<<<blocks, threads, 0, stream>>>(
        reinterpret_cast<const f32x4*>(rewards),
        reinterpret_cast<const i32x4*>(corr),
        reinterpret_cast<f32x4*>(out), Q);
}